// Round 6
// baseline (244.655 us; speedup 1.0000x reference)
//
#include <hip/hip_runtime.h>
#include <hip/hip_fp16.h>

// ---------------------------------------------------------------------------
// score = relu(relu([h[src]|h[dst]]W1+b1)W2+b2)W3+b3
// NEW PATH (ws >= 51.3MB):
//   P = h@W1_top (fp16), Q = h@W1_bot + b1 (fp16)  -- per-NODE precompute
//     pq v6: LDS h-tile stage + LDS transpose epilogue -> coalesced 16B stores
//   edge v6: BARRIER-FREE main loop. Each wave owns all 128 l2-chans of its
//     own 32-edge tile (cm=0..7 from W2 in LDS), layer3 fully in-wave via
//     perm3 -> no cross-wave reduce -> no __syncthreads -> prefetched gathers
//     are never drained by barrier vmcnt(0) (r3-r5's structural stall).
//     2-deep register gather pipeline, launch_bounds(256,2) for VGPR room.
// FALLBACK (small ws): round-1 kernel, f32 gather path.
// ---------------------------------------------------------------------------

typedef _Float16 half8 __attribute__((ext_vector_type(8)));
typedef _Float16 half4_t __attribute__((ext_vector_type(4)));
typedef float    f32x4 __attribute__((ext_vector_type(4)));

#define MFMA16(a, b, c) __builtin_amdgcn_mfma_f32_16x16x32_f16((a), (b), (c), 0, 0, 0)

#define N_NODES_C 100000
#define N_EDGES_C 800000

// ---- new-path ws layout ----
#define W1PF_OFF  0         // 32KB  A-frags of W1_top^T
#define W1QF_OFF  32768     // 32KB  A-frags of W1_bot^T
#define W2F_OFF_N 65536     // 32KB  A-frags of W2^T
#define W3F_OFF_N 98304     // 4KB   A-frags of W3^T (perm3)
#define P16_OFF   131072
#define TBL_HALVES (N_NODES_C * 128)            // 12.8M halves
#define Q16_OFF   (P16_OFF + TBL_HALVES * 2)
#define WS_NEED_NEW ((size_t)Q16_OFF + (size_t)TBL_HALVES * 2)   // ~51.3MB

#define ET 32                         // edges per wave-tile
#define NT_E (N_EDGES_C / ET)         // 25000
#define GRID_E 512                    // 512 blocks x 4 waves = 2048 streams
#define WSTRIDE (GRID_E * 4)
#define NT_N ((N_NODES_C + 63) / 64)  // 1563

// =========================== NEW PATH ======================================

// A-frag pack: frag (cm,kk): lane=16g+rr elem j -> W[32kk+8g+j][16cm+rr]
// w3f uses perm3(g,j)=4g+(j&3)+16*(j>>2) (shared by B-side built in-register).
__global__ void pack_w_new(const float* __restrict__ W1, const float* __restrict__ W2,
                           const float* __restrict__ W3, char* __restrict__ wsb) {
    int i = blockIdx.x * blockDim.x + threadIdx.x;
    _Float16* w1pf = (_Float16*)(wsb + W1PF_OFF);
    _Float16* w1qf = (_Float16*)(wsb + W1QF_OFF);
    _Float16* w2f  = (_Float16*)(wsb + W2F_OFF_N);
    _Float16* w3f  = (_Float16*)(wsb + W3F_OFF_N);
    if (i < 16384) {
        int j = i & 7, lane = (i >> 3) & 63, kk = (i >> 9) & 3, cm = i >> 11;
        int g = lane >> 4, rr = lane & 15;
        int k = 32 * kk + 8 * g + j, n = 16 * cm + rr;
        w1pf[i] = (_Float16)W1[k * 128 + n];
        w1qf[i] = (_Float16)W1[(k + 128) * 128 + n];
        w2f[i]  = (_Float16)W2[k * 128 + n];
    }
    if (i < 2048) {
        int j = i & 7, lane = (i >> 3) & 63, t = i >> 9;
        int g = lane >> 4, rr = lane & 15;
        int k = 32 * t + 4 * g + (j & 3) + 16 * (j >> 2);
        w3f[i] = (rr < 2) ? (_Float16)W3[k * 2 + rr] : (_Float16)0.0f;
    }
}

// pq v6: one 64-node tile per block. Stage h-tile in LDS (swizzled), MFMA,
// scatter fp16 results to the SAME LDS (swizzled), flush coalesced 16B.
__global__ __launch_bounds__(512, 4) void pq_kernel(const float* __restrict__ h,
                                                    const float* __restrict__ b1,
                                                    char* __restrict__ wsb) {
    __shared__ __align__(16) char SMEM[32768];
    float4*   Htile = (float4*)SMEM;        // [64][32] f32x4, slot ^= row&15
    const int tid = threadIdx.x;
    const int w = tid >> 6, l = tid & 63, g = l >> 4, rr = l & 15;
    const int t = w >> 2, cmq = w & 3;
    const half8* wf = (const half8*)(wsb + (t ? W1QF_OFF : W1PF_OFF));
    half8 W1F[2][4];
#pragma unroll
    for (int cm = 0; cm < 2; ++cm)
#pragma unroll
        for (int kk = 0; kk < 4; ++kk)
            W1F[cm][kk] = wf[((2 * cmq + cm) * 4 + kk) * 64 + l];
    f32x4 b1v[2] = {{0.f, 0.f, 0.f, 0.f}, {0.f, 0.f, 0.f, 0.f}};
    if (t == 1) {
#pragma unroll
        for (int cm = 0; cm < 2; ++cm)
            b1v[cm] = *(const f32x4*)(b1 + 16 * (2 * cmq + cm) + 4 * g);
    }

    const int tile = blockIdx.x;
    // ---- stage h-tile (coalesced reads, swizzled ds_write)
    const int slot = l & 31, rhalf = l >> 5;
    float4 sv[4];
    int rows[4];
#pragma unroll
    for (int i = 0; i < 4; ++i) {
        int row = 8 * w + 2 * i + rhalf;
        rows[i] = row;
        int node = tile * 64 + row;
        if (node > N_NODES_C - 1) node = N_NODES_C - 1;
        sv[i] = *(const float4*)(h + (size_t)node * 128 + slot * 4);
    }
#pragma unroll
    for (int i = 0; i < 4; ++i)
        Htile[rows[i] * 32 + (slot ^ (rows[i] & 15))] = sv[i];
    __syncthreads();

    // ---- MFMA
    f32x4 acc[2][4];
#pragma unroll
    for (int cm = 0; cm < 2; ++cm)
#pragma unroll
        for (int ce = 0; ce < 4; ++ce) acc[cm][ce] = f32x4{0.f, 0.f, 0.f, 0.f};
#pragma unroll
    for (int kk = 0; kk < 4; ++kk) {
#pragma unroll
        for (int ce = 0; ce < 4; ++ce) {
            int row = 16 * ce + rr;
            int s0 = kk * 8 + 2 * g;
            float4 fa = Htile[row * 32 + (s0 ^ rr)];
            float4 fb = Htile[row * 32 + ((s0 + 1) ^ rr)];
            half8 b;
            b[0] = (_Float16)fa.x; b[1] = (_Float16)fa.y;
            b[2] = (_Float16)fa.z; b[3] = (_Float16)fa.w;
            b[4] = (_Float16)fb.x; b[5] = (_Float16)fb.y;
            b[6] = (_Float16)fb.z; b[7] = (_Float16)fb.w;
            acc[0][ce] = MFMA16(W1F[0][kk], b, acc[0][ce]);
            acc[1][ce] = MFMA16(W1F[1][kk], b, acc[1][ce]);
        }
    }
    __syncthreads();   // Htile reads done; reuse SMEM as Ytile

    // ---- scatter fp16 results to LDS: Ytile[t][row][256B], off ^= (row&15)<<4
#pragma unroll
    for (int cm = 0; cm < 2; ++cm)
#pragma unroll
        for (int ce = 0; ce < 4; ++ce) {
            int row = 16 * ce + rr;
            f32x4 v = acc[cm][ce] + b1v[cm];
            half4_t o;
            o[0] = (_Float16)v[0]; o[1] = (_Float16)v[1];
            o[2] = (_Float16)v[2]; o[3] = (_Float16)v[3];
            int off = (32 * (2 * cmq + cm) + 8 * g) ^ ((row & 15) << 4);
            *(half4_t*)(SMEM + t * 16384 + row * 256 + off) = o;
        }
    __syncthreads();

    // ---- coalesced flush: 2048 16B chunks, 512 thr x 4 passes
    _Float16* Ptbl = (_Float16*)(wsb + P16_OFF);
    _Float16* Qtbl = (_Float16*)(wsb + Q16_OFF);
#pragma unroll
    for (int p = 0; p < 4; ++p) {
        int c = p * 512 + tid;
        int tt = c >> 10, cc = c & 1023;
        int row = cc >> 4, k = cc & 15;
        int off = (16 * k) ^ ((row & 15) << 4);
        float4 v4 = *(const float4*)(SMEM + tt * 16384 + row * 256 + off);
        int node = tile * 64 + row;
        if (node < N_NODES_C) {
            _Float16* tb = tt ? Qtbl : Ptbl;
            *(float4*)((char*)(tb + (size_t)node * 128) + 16 * k) = v4;
        }
    }
}

// ---------------- edge kernel v6: barrier-free per-wave pipeline ----------

struct GSet { half8 P0[4], P1[4], Q0[4], Q1[4]; };

__device__ __forceinline__ void load_set(GSet& s, const half8* __restrict__ P16,
                                         const half8* __restrict__ Q16, int g,
                                         int s0, int s1, int d0, int d1) {
    const half8* pr0 = P16 + (size_t)s0 * 16 + g;
    const half8* pr1 = P16 + (size_t)s1 * 16 + g;
    const half8* qr0 = Q16 + (size_t)d0 * 16 + g;
    const half8* qr1 = Q16 + (size_t)d1 * 16 + g;
#pragma unroll
    for (int kk = 0; kk < 4; ++kk) {
        s.P0[kk] = pr0[4 * kk];  s.Q0[kk] = qr0[4 * kk];
        s.P1[kk] = pr1[4 * kk];  s.Q1[kk] = qr1[4 * kk];
    }
}

__global__ __launch_bounds__(256, 2) void edge_kernel(
    const int* __restrict__ src, const int* __restrict__ dst,
    const float* __restrict__ b2, const float* __restrict__ b3,
    const char* __restrict__ wsb, float* __restrict__ out) {
    __shared__ half8 W2lds[2048];       // 32KB: frag (cm,kk) at [(cm*4+kk)*64+lane]
    const int tid = threadIdx.x;
    const int w = tid >> 6, l = tid & 63, g = l >> 4, rr = l & 15;
    const half8* w2fg = (const half8*)(wsb + W2F_OFF_N);
    const half8* w3f  = (const half8*)(wsb + W3F_OFF_N);
    const half8* P16  = (const half8*)(wsb + P16_OFF);   // row = 16 x 16B chunks
    const half8* Q16  = (const half8*)(wsb + Q16_OFF);

#pragma unroll
    for (int i = 0; i < 8; ++i) W2lds[i * 256 + tid] = w2fg[i * 256 + tid];

    half8 W3F[4];
#pragma unroll
    for (int tt = 0; tt < 4; ++tt) W3F[tt] = w3f[tt * 64 + l];

    half4_t b2h[8];
#pragma unroll
    for (int cm = 0; cm < 8; ++cm) {
        f32x4 bv = *(const f32x4*)(b2 + 16 * cm + 4 * g);
        b2h[cm][0] = (_Float16)bv[0]; b2h[cm][1] = (_Float16)bv[1];
        b2h[cm][2] = (_Float16)bv[2]; b2h[cm][3] = (_Float16)bv[3];
    }
    const float b30 = b3[0], b31 = b3[1];

    GSet A, B;
    int ia0, ia1, ja0, ja1, ib0, ib1, jb0, jb1;

    int t = blockIdx.x * 4 + w;          // wave-private tile stream
    {
        ia0 = src[t * ET + rr];  ia1 = src[t * ET + 16 + rr];
        ja0 = dst[t * ET + rr];  ja1 = dst[t * ET + 16 + rr];
    }
    load_set(A, P16, Q16, g, ia0, ia1, ja0, ja1);
    {
        int tt = t + WSTRIDE; if (tt >= NT_E) tt = NT_E - 1;
        ib0 = src[tt * ET + rr];  ib1 = src[tt * ET + 16 + rr];
        jb0 = dst[tt * ET + rr];  jb1 = dst[tt * ET + 16 + rr];
    }
    __syncthreads();   // W2lds ready (only barrier in the kernel)

#define COMPUTE_STORE(S, T)                                                     \
    {                                                                           \
        f32x4 acc[8][2];                                                        \
        _Pragma("unroll")                                                       \
        for (int cm = 0; cm < 8; ++cm) {                                        \
            acc[cm][0] = f32x4{0.f, 0.f, 0.f, 0.f};                             \
            acc[cm][1] = f32x4{0.f, 0.f, 0.f, 0.f};                             \
        }                                                                       \
        const half8 hz = {0, 0, 0, 0, 0, 0, 0, 0};                              \
        _Pragma("unroll")                                                       \
        for (int kk = 0; kk < 4; ++kk) {                                        \
            half8 bq0 = __builtin_elementwise_max(S.P0[kk] + S.Q0[kk], hz);     \
            half8 bq1 = __builtin_elementwise_max(S.P1[kk] + S.Q1[kk], hz);     \
            _Pragma("unroll")                                                   \
            for (int cm = 0; cm < 8; ++cm) {                                    \
                half8 wfr = W2lds[(cm * 4 + kk) * 64 + l];                      \
                acc[cm][0] = MFMA16(wfr, bq0, acc[cm][0]);                      \
                acc[cm][1] = MFMA16(wfr, bq1, acc[cm][1]);                      \
            }                                                                   \
        }                                                                       \
        f32x4 D3[2] = {{0.f, 0.f, 0.f, 0.f}, {0.f, 0.f, 0.f, 0.f}};             \
        _Pragma("unroll")                                                       \
        for (int tt = 0; tt < 4; ++tt)                                          \
            _Pragma("unroll")                                                   \
            for (int ce = 0; ce < 2; ++ce) {                                    \
                half8 bf;                                                       \
                _Pragma("unroll")                                               \
                for (int j = 0; j < 8; ++j) {                                   \
                    const int cm = 2 * tt + (j >> 2), r = j & 3;                \
                    float v = acc[cm][ce][r] + (float)b2h[cm][r];               \
                    v = v > 0.f ? v : 0.f;                                      \
                    bf[j] = (_Float16)v;                                        \
                }                                                               \
                D3[ce] = MFMA16(W3F[tt], bf, D3[ce]);                           \
            }                                                                   \
        if (g == 0) {                                                           \
            _Pragma("unroll")                                                   \
            for (int ce = 0; ce < 2; ++ce) {                                    \
                float2 ov;                                                      \
                ov.x = D3[ce][0] + b30;                                         \
                ov.y = D3[ce][1] + b31;                                         \
                *(float2*)(out + (size_t)((T) * ET + 16 * ce + rr) * 2) = ov;   \
            }                                                                   \
        }                                                                       \
    }

    for (;;) {
        // A holds data(t); B's gathers for t+S issue now, never drained early.
        load_set(B, P16, Q16, g, ib0, ib1, jb0, jb1);
        {
            int tt = t + 2 * WSTRIDE; if (tt >= NT_E) tt = NT_E - 1;
            ia0 = src[tt * ET + rr];  ia1 = src[tt * ET + 16 + rr];
            ja0 = dst[tt * ET + rr];  ja1 = dst[tt * ET + 16 + rr];
        }
        COMPUTE_STORE(A, t);
        t += WSTRIDE;
        if (t >= NT_E) break;

        load_set(A, P16, Q16, g, ia0, ia1, ja0, ja1);
        {
            int tt = t + 2 * WSTRIDE; if (tt >= NT_E) tt = NT_E - 1;
            ib0 = src[tt * ET + rr];  ib1 = src[tt * ET + 16 + rr];
            jb0 = dst[tt * ET + rr];  jb1 = dst[tt * ET + 16 + rr];
        }
        COMPUTE_STORE(B, t);
        t += WSTRIDE;
        if (t >= NT_E) break;
    }
#undef COMPUTE_STORE
}

// =========================== FALLBACK (round-1, f32 gather) ================

#define NT_O   12500
#define GRID_O 512
#define OW1_OFF 0
#define OW2_OFF 65536
#define OW3_OFF 98304

__global__ void pack_w_old(const float* __restrict__ W1, const float* __restrict__ W2,
                           const float* __restrict__ W3, char* __restrict__ wsb) {
    int i = blockIdx.x * blockDim.x + threadIdx.x;
    _Float16* w1f = (_Float16*)(wsb + OW1_OFF);
    _Float16* w2f = (_Float16*)(wsb + OW2_OFF);
    _Float16* w3f = (_Float16*)(wsb + OW3_OFF);
    if (i < 32768) {
        int j = i & 7, lx = (i >> 3) & 63, kk = (i >> 9) & 7, t = i >> 12;
        int k = 32 * kk + 8 * (lx >> 4) + j, n = 16 * t + (lx & 15);
        w1f[i] = (_Float16)W1[k * 128 + n];
    }
    if (i < 16384) {
        int j = i & 7, lx = (i >> 3) & 63, kk = (i >> 9) & 3, t = i >> 11;
        int k = 32 * kk + 8 * (lx >> 4) + j, n = 16 * t + (lx & 15);
        w2f[i] = (_Float16)W2[k * 128 + n];
    }
    if (i < 2048) {
        int j = i & 7, lx = (i >> 3) & 63, kk = i >> 9;
        int k = 32 * kk + 8 * (lx >> 4) + j, n = lx & 15;
        w3f[i] = (n < 2) ? (_Float16)W3[k * 2 + n] : (_Float16)0.0f;
    }
}

__device__ inline half8 ldfrag_f32(const float* __restrict__ h, int idx, int kk, int g) {
    const float4* p = (const float4*)(h + (size_t)idx * 128 + (kk & 3) * 32 + g * 8);
    float4 a = p[0], b = p[1];
    half8 o;
    o[0] = (_Float16)a.x; o[1] = (_Float16)a.y; o[2] = (_Float16)a.z; o[3] = (_Float16)a.w;
    o[4] = (_Float16)b.x; o[5] = (_Float16)b.y; o[6] = (_Float16)b.z; o[7] = (_Float16)b.w;
    return o;
}

__global__ __launch_bounds__(256, 2) void edge_mlp_old(
    const float* __restrict__ h, const int* __restrict__ src, const int* __restrict__ dst,
    const float* __restrict__ b1, const float* __restrict__ b2, const float* __restrict__ b3,
    const char* __restrict__ wsb, float* __restrict__ out) {
    __shared__ half8 Xp [32 * 64];
    __shared__ half8 Y1p[16 * 64];
    __shared__ half8 Y2p[16 * 64];
    const int tid = threadIdx.x;
    const int w = tid >> 6, l = tid & 63;
    const int g = l >> 4, rr = l & 15;
    const int ghalf = rr >> 3, j7 = rr & 7;
    half8 W1F[2][8], W2F[2][4], W3F[4];
    {
        const half8* p1 = (const half8*)(wsb + OW1_OFF);
        const half8* p2 = (const half8*)(wsb + OW2_OFF);
        const half8* p3 = (const half8*)(wsb + OW3_OFF);
#pragma unroll
        for (int nt = 0; nt < 2; ++nt)
#pragma unroll
            for (int kk = 0; kk < 8; ++kk) W1F[nt][kk] = p1[((w * 2 + nt) * 8 + kk) * 64 + l];
#pragma unroll
        for (int nt = 0; nt < 2; ++nt)
#pragma unroll
            for (int kk = 0; kk < 4; ++kk) W2F[nt][kk] = p2[((w * 2 + nt) * 4 + kk) * 64 + l];
#pragma unroll
        for (int kk = 0; kk < 4; ++kk) W3F[kk] = p3[kk * 64 + l];
    }
    float b1r[2], b2r[2];
    b1r[0] = b1[w * 32 + rr];      b1r[1] = b1[w * 32 + 16 + rr];
    b2r[0] = b2[w * 32 + rr];      b2r[1] = b2[w * 32 + 16 + rr];
    const float b3r = (rr < 2) ? b3[rr] : 0.0f;
    _Float16* y1h = (_Float16*)Y1p;
    _Float16* y2h = (_Float16*)Y2p;
    int   idxn[8];
    half8 xt[8];
    int tile = blockIdx.x;
#pragma unroll
    for (int i = 0; i < 8; i++) {
        int bidx = w * 8 + i, kk = bidx >> 2;
        int e = ((i & 3) << 4) + rr;
        int id = (kk < 4 ? src : dst)[tile * 64 + e];
        xt[i] = ldfrag_f32(h, id, kk, g);
    }
#pragma unroll
    for (int i = 0; i < 8; i++) Xp[(w * 8 + i) * 64 + l] = xt[i];
    {
        int t1 = tile + GRID_O; if (t1 >= NT_O) t1 = NT_O - 1;
#pragma unroll
        for (int i = 0; i < 8; i++) {
            int bidx = w * 8 + i, kk = bidx >> 2;
            int e = ((i & 3) << 4) + rr;
            idxn[i] = (kk < 4 ? src : dst)[t1 * 64 + e];
        }
    }
    __syncthreads();
    for (; tile < NT_O; tile += GRID_O) {
        f32x4 acc1[4][2];
#pragma unroll
        for (int mt = 0; mt < 4; ++mt) {
            acc1[mt][0] = f32x4{0.f, 0.f, 0.f, 0.f};
            acc1[mt][1] = f32x4{0.f, 0.f, 0.f, 0.f};
        }
#pragma unroll
        for (int kk = 0; kk < 8; ++kk) {
            half8 a[4];
#pragma unroll
            for (int mt = 0; mt < 4; ++mt) a[mt] = Xp[(kk * 4 + mt) * 64 + l];
#pragma unroll
            for (int mt = 0; mt < 4; ++mt) {
                acc1[mt][0] = MFMA16(a[mt], W1F[0][kk], acc1[mt][0]);
                acc1[mt][1] = MFMA16(a[mt], W1F[1][kk], acc1[mt][1]);
            }
        }
#pragma unroll
        for (int i = 0; i < 8; i++) {
            int kk = (w * 8 + i) >> 2;
            xt[i] = ldfrag_f32(h, idxn[i], kk, g);
        }
        {
            int t2 = tile + 2 * GRID_O; if (t2 >= NT_O) t2 = NT_O - 1;
#pragma unroll
            for (int i = 0; i < 8; i++) {
                int bidx = w * 8 + i, kk = bidx >> 2;
                int e = ((i & 3) << 4) + rr;
                idxn[i] = (kk < 4 ? src : dst)[t2 * 64 + e];
            }
        }
#pragma unroll
        for (int mt = 0; mt < 4; ++mt)
#pragma unroll
            for (int nt = 0; nt < 2; ++nt) {
                float bb = b1r[nt];
#pragma unroll
                for (int r = 0; r < 4; ++r) {
                    float v = acc1[mt][nt][r] + bb;
                    v = v > 0.f ? v : 0.f;
                    y1h[(((w * 4 + mt) * 64 + 16 * (2 * nt + ghalf) + 4 * g + r) << 3) + j7] =
                        (_Float16)v;
                }
            }
        __syncthreads();
        f32x4 acc2[4][2];
#pragma unroll
        for (int mt = 0; mt < 4; ++mt) {
            acc2[mt][0] = f32x4{0.f, 0.f, 0.f, 0.f};
            acc2[mt][1] = f32x4{0.f, 0.f, 0.f, 0.f};
        }
#pragma unroll
        for (int kk = 0; kk < 4; ++kk) {
            half8 a[4];
#pragma unroll
            for (int mt = 0; mt < 4; ++mt) a[mt] = Y1p[(kk * 4 + mt) * 64 + l];
#pragma unroll
            for (int mt = 0; mt < 4; ++mt) {
                acc2[mt][0] = MFMA16(a[mt], W2F[0][kk], acc2[mt][0]);
                acc2[mt][1] = MFMA16(a[mt], W2F[1][kk], acc2[mt][1]);
            }
        }
#pragma unroll
        for (int mt = 0; mt < 4; ++mt)
#pragma unroll
            for (int nt = 0; nt < 2; ++nt) {
                float bb = b2r[nt];
#pragma unroll
                for (int r = 0; r < 4; ++r) {
                    float v = acc2[mt][nt][r] + bb;
                    v = v > 0.f ? v : 0.f;
                    y2h[(((w * 4 + mt) * 64 + 16 * (2 * nt + ghalf) + 4 * g + r) << 3) + j7] =
                        (_Float16)v;
                }
            }
        __syncthreads();
        f32x4 acc3 = {0.f, 0.f, 0.f, 0.f};
#pragma unroll
        for (int kk = 0; kk < 4; ++kk) {
            half8 a = Y2p[(kk * 4 + w) * 64 + l];
            acc3 = MFMA16(a, W3F[kk], acc3);
        }
        if (rr < 2) {
#pragma unroll
            for (int r = 0; r < 4; ++r) {
                int m = w * 16 + 4 * g + r;
                out[(tile * 64 + m) * 2 + rr] = acc3[r] + b3r;
            }
        }
#pragma unroll
        for (int i = 0; i < 8; i++) Xp[(w * 8 + i) * 64 + l] = xt[i];
        __syncthreads();
    }
}

// --------------------------- launch ----------------------------------------

extern "C" void kernel_launch(void* const* d_in, const int* in_sizes, int n_in,
                              void* d_out, int out_size, void* d_ws, size_t ws_size,
                              hipStream_t stream) {
    const float* h   = (const float*)d_in[0];
    const int*   src = (const int*)d_in[1];
    const int*   dst = (const int*)d_in[2];
    const float* W1  = (const float*)d_in[3];
    const float* b1  = (const float*)d_in[4];
    const float* W2  = (const float*)d_in[5];
    const float* b2  = (const float*)d_in[6];
    const float* W3  = (const float*)d_in[7];
    const float* b3  = (const float*)d_in[8];
    char*  wsb = (char*)d_ws;
    float* out = (float*)d_out;
    (void)in_sizes; (void)n_in; (void)out_size;

    if (ws_size >= WS_NEED_NEW) {
        pack_w_new<<<64, 256, 0, stream>>>(W1, W2, W3, wsb);
        pq_kernel<<<NT_N, 512, 0, stream>>>(h, b1, wsb);
        edge_kernel<<<GRID_E, 256, 0, stream>>>(src, dst, b2, b3, wsb, out);
    } else {
        pack_w_old<<<128, 256, 0, stream>>>(W1, W2, W3, wsb);
        edge_mlp_old<<<GRID_O, 256, 0, stream>>>(h, src, dst, b1, b2, b3, wsb, out);
    }
}